// Round 4
// baseline (13839.502 us; speedup 1.0000x reference)
//
#include <hip/hip_runtime.h>
#include <cstdint>
#include <cstddef>

typedef _Float16 f16;
typedef _Float16 half2_t __attribute__((ext_vector_type(2)));
typedef _Float16 half4_t __attribute__((ext_vector_type(4)));
typedef _Float16 half8_t __attribute__((ext_vector_type(8)));
typedef float floatx4 __attribute__((ext_vector_type(4)));

__device__ __forceinline__ float fdot2u(uint32_t w, uint32_t h, float acc) {
#if __has_builtin(__builtin_amdgcn_fdot2)
    return __builtin_amdgcn_fdot2(__builtin_bit_cast(half2_t, w),
                                  __builtin_bit_cast(half2_t, h), acc, false);
#else
    half2_t a = __builtin_bit_cast(half2_t, w);
    half2_t b = __builtin_bit_cast(half2_t, h);
    return acc + (float)a[0] * (float)b[0] + (float)a[1] * (float)b[1];
#endif
}

// ---------------- fp32 -> f16 conversion ----------------
__global__ void cvt_kernel(const float* __restrict__ in, f16* __restrict__ out, int n4) {
    int i = blockIdx.x * blockDim.x + threadIdx.x;
    int stride = gridDim.x * blockDim.x;
    const float4* in4 = (const float4*)in;
    half4_t* out4 = (half4_t*)out;
    for (; i < n4; i += stride) {
        float4 v = in4[i];
        half4_t h = {(f16)v.x, (f16)v.y, (f16)v.z, (f16)v.w};
        out4[i] = h;
    }
}

// ---------------- bias sum ----------------
__global__ void bsum_kernel(const float* __restrict__ a, const float* __restrict__ b,
                            float* __restrict__ o) {
    int i = threadIdx.x;
    o[i] = a[i] + b[i];
}

// ---------------- pack W_hh for the half-split recurrence ----------------
// Block (row, half) owns j in [half*256, half*256+256), all k in [0,512).
// Thread tid (0..1023): kg = tid>>6 (k-group of 32), jq = tid&63 (j = half*256 + 4*jq + r).
// Per-thread dword idx = c*16 + r*4 + q  (c = k-chunk of 8 in group: 0..3, q = k-pair: 0..3),
// i.e. k = kg*32 + c*8 + q*2.  Layout: wp[half][idx][tid] (coalesced dword loads).
__global__ void pack_whh(const float* __restrict__ W, uint32_t* __restrict__ wp) {
    int id = blockIdx.x * 256 + threadIdx.x;   // 131072 = 512*256 pairs
    int j = id >> 8;        // 0..511
    int kp = id & 255;      // 0..255
    int k = kp * 2;
    int half = j >> 8;
    int jl = j & 255;
    int jq = jl >> 2, r = jl & 3;
    int kg = k >> 5;            // 0..15
    int c = (k >> 3) & 3;
    int q = (k >> 1) & 3;
    int tid = kg * 64 + jq;
    int idx = c * 16 + r * 4 + q;
    uint32_t lo = (uint32_t)__builtin_bit_cast(uint16_t, (f16)W[(size_t)j * 512 + k]);
    uint32_t hi = (uint32_t)__builtin_bit_cast(uint16_t, (f16)W[(size_t)j * 512 + k + 1]);
    wp[((size_t)half * 64 + idx) * 1024 + tid] = (hi << 16) | lo;
}

// ---------------- xproj GEMM (unchanged) ----------------
__global__ __launch_bounds__(256) void gemm_xp(const f16* __restrict__ A,
                                               const f16* __restrict__ Bw,
                                               const float* __restrict__ bias,
                                               f16* __restrict__ C) {
    const int bn = blockIdx.x & 3;
    const int bm = blockIdx.x >> 2;
    const int tid = threadIdx.x;
    const int w = tid >> 6, l = tid & 63;
    const int wr = w >> 1, wc = w & 1;
    __shared__ f16 As[128 * 32];
    __shared__ f16 Bs[128 * 32];
    floatx4 acc[4][4] = {};
    const int lr = l & 15, lk = (l >> 4) * 8;
    for (int kk = 0; kk < 512; kk += 32) {
        __syncthreads();
        uint4 av[2], bv[2];
#pragma unroll
        for (int s = 0; s < 2; ++s) {
            int chunk = tid + s * 256;
            int row = chunk >> 2;
            int colh = (chunk & 3) * 8;
            av[s] = *(const uint4*)&A[((size_t)(bm * 128 + row)) * 512 + kk + colh];
            bv[s] = *(const uint4*)&Bw[((size_t)(bn * 128 + row)) * 512 + kk + colh];
        }
#pragma unroll
        for (int s = 0; s < 2; ++s) {
            int chunk = tid + s * 256;
            *(uint4*)&As[chunk * 8] = av[s];
            *(uint4*)&Bs[chunk * 8] = bv[s];
        }
        __syncthreads();
        half8_t af[4], bf[4];
#pragma unroll
        for (int m = 0; m < 4; ++m)
            af[m] = *(const half8_t*)&As[(wr * 64 + m * 16 + lr) * 32 + lk];
#pragma unroll
        for (int n = 0; n < 4; ++n)
            bf[n] = *(const half8_t*)&Bs[(wc * 64 + n * 16 + lr) * 32 + lk];
#pragma unroll
        for (int m = 0; m < 4; ++m)
#pragma unroll
            for (int n = 0; n < 4; ++n)
                acc[m][n] = __builtin_amdgcn_mfma_f32_16x16x32_f16(af[m], bf[n], acc[m][n], 0, 0, 0);
    }
    float bz[4];
#pragma unroll
    for (int n = 0; n < 4; ++n) bz[n] = bias[bn * 128 + wc * 64 + n * 16 + lr];
    const int lq = l >> 4;
#pragma unroll
    for (int m = 0; m < 4; ++m)
#pragma unroll
        for (int n = 0; n < 4; ++n)
#pragma unroll
            for (int e = 0; e < 4; ++e) {
                int row = bm * 128 + wr * 64 + m * 16 + lq * 4 + e;
                int col = bn * 128 + wc * 64 + n * 16 + lr;
                C[(size_t)row * 512 + col] = (f16)(acc[m][n][e] + bz[n]);
            }
}

// ---------------- half-split persistent recurrence ----------------
// 128 blocks = (64 rows) x (2 halves). W fully VGPR-resident (64 dwords/thread).
// Halves exchange 256 f16 of h per step via agent-scope atomics + flags.

#define FOR_Q(M, c, r) M(c, r, 0) M(c, r, 1) M(c, r, 2) M(c, r, 3)
#define FOR_R(M, c) FOR_Q(M, c, 0) FOR_Q(M, c, 1) FOR_Q(M, c, 2) FOR_Q(M, c, 3)
#define FOR_ALL(M) FOR_R(M, 0) FOR_R(M, 1) FOR_R(M, 2) FOR_R(M, 3)
#define FOR_CQ(M) M(0,0) M(0,1) M(0,2) M(0,3) M(1,0) M(1,1) M(1,2) M(1,3) \
                  M(2,0) M(2,1) M(2,2) M(2,3) M(3,0) M(3,1) M(3,2) M(3,3)

#define DECLW(c, r, q) uint32_t W_##c##_##r##_##q;
#define LOADW(c, r, q) W_##c##_##r##_##q = wpb[(size_t)(((c)*16 + (r)*4 + (q)) * 1024) + tid];
#define DOTQ(c, r, q) a##r = fdot2u(W_##c##_##r##_##q, hq##q, a##r);

#define CHUNK_OWN(c)                                                   \
    {                                                                  \
        uint4 hv = *(const uint4*)(hrow + (c) * 4);                    \
        uint32_t hq0 = hv.x, hq1 = hv.y, hq2 = hv.z, hq3 = hv.w;       \
        FOR_Q(DOTQ, c, 0) FOR_Q(DOTQ, c, 1)                            \
        FOR_Q(DOTQ, c, 2) FOR_Q(DOTQ, c, 3)                            \
    }

#define DECLHP(c, q) uint32_t HP_##c##_##q = 0;
#define LOADHP(c, q) HP_##c##_##q = __hip_atomic_load(payR + ((c)*4 + (q)), \
                        __ATOMIC_RELAXED, __HIP_MEMORY_SCOPE_AGENT);

#define CHUNK_PAY(c)                                                   \
    {                                                                  \
        uint32_t hq0 = HP_##c##_0, hq1 = HP_##c##_1,                   \
                 hq2 = HP_##c##_2, hq3 = HP_##c##_3;                   \
        FOR_Q(DOTQ, c, 0) FOR_Q(DOTQ, c, 1)                            \
        FOR_Q(DOTQ, c, 2) FOR_Q(DOTQ, c, 3)                            \
    }

__global__ __launch_bounds__(1024)
__attribute__((amdgpu_waves_per_eu(4, 4)))
void rnn_kernel(const f16* __restrict__ xp, const uint32_t* __restrict__ wp,
                f16* __restrict__ hout, unsigned short* __restrict__ pay,
                int* __restrict__ flags, int store_all) {
    const int bid = blockIdx.x;
    const int row = bid & 63;
    const int half = bid >> 6;           // partner block = bid ^ 64 (same XCD under round-robin)
    const int phalf = 1 - half;
    const int tid = threadIdx.x;
    const int kg = tid >> 6;             // 0..15, wave-uniform
    const int jq = tid & 63;
    const bool own = (kg >> 3) == half;  // this wave's k-range lies in our own j-half
    __shared__ alignas(16) f16 hbuf[2][256];
    __shared__ float part[16][256];
    __shared__ f16 pad_[34816];          // 68KB pad -> ~85KB LDS -> exactly 1 block/CU

    const uint32_t* wpb = wp + (size_t)half * 64 * 1024;
    FOR_ALL(DECLW)
    FOR_ALL(LOADW)

    if (tid < 256) hbuf[0][tid] = (f16)0.f;
    if (store_all == 0x7fffffff) { pad_[tid] = (f16)1.f; hout[0] = pad_[tid]; }  // keep pad_
    __syncthreads();

    const f16* xprow = xp + (size_t)row * 512 * 512 + half * 256;
    f16* houtb = store_all ? hout + (size_t)row * 512 * 512 + half * 256
                           : hout + (size_t)row * 512 + half * 256;

    const int koff = (kg & 7) * 32;      // own-case: local h offset (f16 idx)
    const int pk2 = (kg & 7) * 16;       // partner-case: u32 offset within partner half
    uint32_t* pay32 = (uint32_t*)pay;
    int* flagSelf = flags + row * 2 + half;
    int* flagPartner = flags + row * 2 + phalf;

    int p = 0;
    for (int t = 0; t < 512; ++t) {
        float xpv = 0.f;
        if (tid < 256) xpv = (float)xprow[(size_t)t * 512 + tid];

        float a0 = 0.f, a1 = 0.f, a2 = 0.f, a3 = 0.f;
        if (own) {
            const uint32_t* hrow = (const uint32_t*)&hbuf[p][koff];
            CHUNK_OWN(0) CHUNK_OWN(1) CHUNK_OWN(2) CHUNK_OWN(3)
        } else {
            FOR_CQ(DECLHP)
            if (t > 0) {
                while (__hip_atomic_load(flagPartner, __ATOMIC_ACQUIRE,
                                         __HIP_MEMORY_SCOPE_AGENT) < t) {}
                const uint32_t* payR =
                    pay32 + ((size_t)((t & 1) * 64 + row) * 2 + phalf) * 128 + pk2;
                FOR_CQ(LOADHP)
            }
            CHUNK_PAY(0) CHUNK_PAY(1) CHUNK_PAY(2) CHUNK_PAY(3)
        }
        *(float4*)&part[kg][jq * 4] = make_float4(a0, a1, a2, a3);
        __syncthreads();
        if (tid < 256) {
            float s = xpv;
#pragma unroll
            for (int g = 0; g < 16; ++g) s += part[g][tid];
            float e = __expf(2.0f * s);
            float hn = 1.0f - 2.0f / (1.0f + e);
            f16 hh = (f16)hn;
            hbuf[p ^ 1][tid] = hh;
            unsigned short hu = __builtin_bit_cast(unsigned short, hh);
            __hip_atomic_store(pay + ((size_t)(((t + 1) & 1) * 64 + row) * 2 + half) * 256 + tid,
                               hu, __ATOMIC_RELAXED, __HIP_MEMORY_SCOPE_AGENT);
            if (store_all) houtb[(size_t)t * 512 + tid] = hh;
            else if (t == 511) houtb[tid] = hh;
        }
        __syncthreads();   // drains vmcnt -> payload stores visible before flag
        if (tid == 0)
            __hip_atomic_store(flagSelf, t + 1, __ATOMIC_RELEASE, __HIP_MEMORY_SCOPE_AGENT);
        p ^= 1;
    }
}

// ---------------- final FC ----------------
__global__ __launch_bounds__(512) void fc_kernel(const f16* __restrict__ h1,
                                                 const float* __restrict__ Wfc,
                                                 const float* __restrict__ bfc,
                                                 float* __restrict__ out) {
    int b = blockIdx.x, tid = threadIdx.x;
    __shared__ float red[8];
    float v = (float)h1[(size_t)b * 512 + tid] * Wfc[tid];
#pragma unroll
    for (int off = 32; off > 0; off >>= 1) v += __shfl_down(v, off, 64);
    if ((tid & 63) == 0) red[tid >> 6] = v;
    __syncthreads();
    if (tid == 0) {
        float s = bfc[0];
#pragma unroll
        for (int g = 0; g < 8; ++g) s += red[g];
        out[b] = s;
    }
}

extern "C" void kernel_launch(void* const* d_in, const int* in_sizes, int n_in,
                              void* d_out, int out_size, void* d_ws, size_t ws_size,
                              hipStream_t stream) {
    const float* x    = (const float*)d_in[0];
    const float* Wih0 = (const float*)d_in[1];
    const float* Whh0 = (const float*)d_in[2];
    const float* bih0 = (const float*)d_in[3];
    const float* bhh0 = (const float*)d_in[4];
    const float* Wih1 = (const float*)d_in[5];
    const float* Whh1 = (const float*)d_in[6];
    const float* bih1 = (const float*)d_in[7];
    const float* bhh1 = (const float*)d_in[8];
    const float* Wfc  = (const float*)d_in[9];
    const float* bfc  = (const float*)d_in[10];
    float* out = (float*)d_out;

    char* ws = (char*)d_ws;
    size_t off = 0;
    auto alloc = [&](size_t bytes) -> void* {
        void* p = ws + off;
        off += (bytes + 255) & ~(size_t)255;
        return p;
    };
    const size_t MTD = (size_t)64 * 512 * 512;
    f16* x16    = (f16*)alloc(MTD * 2);
    f16* h016   = (f16*)alloc(MTD * 2);
    f16* xpb    = (f16*)alloc(MTD * 2);
    f16* wih016 = (f16*)alloc((size_t)512 * 512 * 2);
    f16* wih116 = (f16*)alloc((size_t)512 * 512 * 2);
    uint32_t* wp0 = (uint32_t*)alloc((size_t)131072 * 4);
    uint32_t* wp1 = (uint32_t*)alloc((size_t)131072 * 4);
    float* bs0 = (float*)alloc(512 * 4);
    float* bs1 = (float*)alloc(512 * 4);
    f16* h1last = (f16*)alloc((size_t)64 * 512 * 2);
    unsigned short* pay0 = (unsigned short*)alloc((size_t)2 * 64 * 2 * 256 * 2);  // 128KB
    unsigned short* pay1 = (unsigned short*)alloc((size_t)2 * 64 * 2 * 256 * 2);
    int* flags = (int*)alloc(256 * 4);   // [layer][row][half] = 2*64*2 ints

    // prep
    cvt_kernel<<<2048, 256, 0, stream>>>(x, x16, (int)(MTD / 4));
    cvt_kernel<<<256, 256, 0, stream>>>(Wih0, wih016, 512 * 512 / 4);
    cvt_kernel<<<256, 256, 0, stream>>>(Wih1, wih116, 512 * 512 / 4);
    bsum_kernel<<<1, 512, 0, stream>>>(bih0, bhh0, bs0);
    bsum_kernel<<<1, 512, 0, stream>>>(bih1, bhh1, bs1);
    pack_whh<<<512, 256, 0, stream>>>(Whh0, wp0);
    pack_whh<<<512, 256, 0, stream>>>(Whh1, wp1);
    hipMemsetAsync(flags, 0, 256 * 4, stream);

    // layer 0
    gemm_xp<<<1024, 256, 0, stream>>>(x16, wih016, bs0, xpb);
    rnn_kernel<<<128, 1024, 0, stream>>>(xpb, wp0, h016, pay0, flags, 1);
    // layer 1
    gemm_xp<<<1024, 256, 0, stream>>>(h016, wih116, bs1, xpb);
    rnn_kernel<<<128, 1024, 0, stream>>>(xpb, wp1, h1last, pay1, flags + 128, 0);
    // head
    fc_kernel<<<64, 512, 0, stream>>>(h1last, Wfc, bfc, out);
}

// Round 5
// 1570.577 us; speedup vs baseline: 8.8117x; 8.8117x over previous
//
#include <hip/hip_runtime.h>
#include <cstdint>
#include <cstddef>

typedef _Float16 f16;
typedef _Float16 half2_t __attribute__((ext_vector_type(2)));
typedef _Float16 half4_t __attribute__((ext_vector_type(4)));
typedef _Float16 half8_t __attribute__((ext_vector_type(8)));
typedef float floatx4 __attribute__((ext_vector_type(4)));

__device__ __forceinline__ float fdot2u(uint32_t w, uint32_t h, float acc) {
#if __has_builtin(__builtin_amdgcn_fdot2)
    return __builtin_amdgcn_fdot2(__builtin_bit_cast(half2_t, w),
                                  __builtin_bit_cast(half2_t, h), acc, false);
#else
    half2_t a = __builtin_bit_cast(half2_t, w);
    half2_t b = __builtin_bit_cast(half2_t, h);
    return acc + (float)a[0] * (float)b[0] + (float)a[1] * (float)b[1];
#endif
}

__device__ __forceinline__ void poll_ge(int* f, int v) {
    while (__hip_atomic_load(f, __ATOMIC_ACQUIRE, __HIP_MEMORY_SCOPE_AGENT) < v)
        __builtin_amdgcn_s_sleep(32);
}

__device__ __forceinline__ void publish(int* f, int v) {
    __threadfence();
    __hip_atomic_store(f, v, __ATOMIC_RELEASE, __HIP_MEMORY_SCOPE_AGENT);
}

// ---------------- fp32 -> f16 conversion ----------------
__global__ void cvt_kernel(const float* __restrict__ in, f16* __restrict__ out, int n4) {
    int i = blockIdx.x * blockDim.x + threadIdx.x;
    int stride = gridDim.x * blockDim.x;
    const float4* in4 = (const float4*)in;
    half4_t* out4 = (half4_t*)out;
    for (; i < n4; i += stride) {
        float4 v = in4[i];
        half4_t h = {(f16)v.x, (f16)v.y, (f16)v.z, (f16)v.w};
        out4[i] = h;
    }
}

// ---------------- bias sum ----------------
__global__ void bsum_kernel(const float* __restrict__ a, const float* __restrict__ b,
                            float* __restrict__ o) {
    int i = threadIdx.x;
    o[i] = a[i] + b[i];
}

// ---------------- pack W into per-thread matvec layout (round-3, proven) ----------------
// out_j = sum_k W[j][k] * in[k].  Thread tid: kg=tid>>7, jq=tid&127 (j=4*jq+r).
// idx = c*16+r*4+q (c: k-chunk of 8 in group, q: k-pair), k = 64*kg + 8*c + 2*q.
// idx<96: reg-resident [idx][tid]; idx>=96 (c=6,7): LDS [g][tid][4], g=(c-6)*4+r.
__global__ void pack_whh(const float* __restrict__ W, uint32_t* __restrict__ wp) {
    int id = blockIdx.x * 256 + threadIdx.x;   // 131072 pairs
    int j = id >> 8;
    int kp = id & 255;
    int k = kp * 2;
    int jq = j >> 2, r = j & 3;
    int kg = k >> 6, c = (k & 63) >> 3, q = (k & 7) >> 1;
    int tid = kg * 128 + jq;
    int idx = c * 16 + r * 4 + q;
    uint32_t lo = (uint32_t)__builtin_bit_cast(uint16_t, (f16)W[(size_t)j * 512 + k]);
    uint32_t hi = (uint32_t)__builtin_bit_cast(uint16_t, (f16)W[(size_t)j * 512 + k + 1]);
    size_t off;
    if (idx < 96) off = (size_t)idx * 1024 + tid;
    else          off = (size_t)96 * 1024 + (size_t)((((c - 6) * 4 + r) * 1024 + tid)) * 4 + q;
    wp[off] = (hi << 16) | lo;
}

// ---------------- xproj GEMM for layer 0 (proven) ----------------
__global__ __launch_bounds__(256) void gemm_xp(const f16* __restrict__ A,
                                               const f16* __restrict__ Bw,
                                               const float* __restrict__ bias,
                                               f16* __restrict__ C) {
    const int bn = blockIdx.x & 3;
    const int bm = blockIdx.x >> 2;
    const int tid = threadIdx.x;
    const int w = tid >> 6, l = tid & 63;
    const int wr = w >> 1, wc = w & 1;
    __shared__ f16 As[128 * 32];
    __shared__ f16 Bs[128 * 32];
    floatx4 acc[4][4] = {};
    const int lr = l & 15, lk = (l >> 4) * 8;
    for (int kk = 0; kk < 512; kk += 32) {
        __syncthreads();
        uint4 av[2], bv[2];
#pragma unroll
        for (int s = 0; s < 2; ++s) {
            int chunk = tid + s * 256;
            int row = chunk >> 2;
            int colh = (chunk & 3) * 8;
            av[s] = *(const uint4*)&A[((size_t)(bm * 128 + row)) * 512 + kk + colh];
            bv[s] = *(const uint4*)&Bw[((size_t)(bn * 128 + row)) * 512 + kk + colh];
        }
#pragma unroll
        for (int s = 0; s < 2; ++s) {
            int chunk = tid + s * 256;
            *(uint4*)&As[chunk * 8] = av[s];
            *(uint4*)&Bs[chunk * 8] = bv[s];
        }
        __syncthreads();
        half8_t af[4], bf[4];
#pragma unroll
        for (int m = 0; m < 4; ++m)
            af[m] = *(const half8_t*)&As[(wr * 64 + m * 16 + lr) * 32 + lk];
#pragma unroll
        for (int n = 0; n < 4; ++n)
            bf[n] = *(const half8_t*)&Bs[(wc * 64 + n * 16 + lr) * 32 + lk];
#pragma unroll
        for (int m = 0; m < 4; ++m)
#pragma unroll
            for (int n = 0; n < 4; ++n)
                acc[m][n] = __builtin_amdgcn_mfma_f32_16x16x32_f16(af[m], bf[n], acc[m][n], 0, 0, 0);
    }
    float bz[4];
#pragma unroll
    for (int n = 0; n < 4; ++n) bz[n] = bias[bn * 128 + wc * 64 + n * 16 + lr];
    const int lq = l >> 4;
#pragma unroll
    for (int m = 0; m < 4; ++m)
#pragma unroll
        for (int n = 0; n < 4; ++n)
#pragma unroll
            for (int e = 0; e < 4; ++e) {
                int row = bm * 128 + wr * 64 + m * 16 + lq * 4 + e;
                int col = bn * 128 + wc * 64 + n * 16 + lr;
                C[(size_t)row * 512 + col] = (f16)(acc[m][n][e] + bz[n]);
            }
}

// ---------------- fused 3-stage pipeline ----------------
// 192 blocks: [0,64) layer-0 rnn rows; [64,128) projection xp1=Wih1*h0+bias; [128,192) layer-1 rnn.
// All use round-3's persistent matvec: 96 W-dwords in named regs, 32 in LDS.

#define FOR_Q(M, c, r) M(c, r, 0) M(c, r, 1) M(c, r, 2) M(c, r, 3)
#define FOR_R(M, c) FOR_Q(M, c, 0) FOR_Q(M, c, 1) FOR_Q(M, c, 2) FOR_Q(M, c, 3)
#define FOR_ALL(M) FOR_R(M, 0) FOR_R(M, 1) FOR_R(M, 2) FOR_R(M, 3) FOR_R(M, 4) FOR_R(M, 5)

#define DECLW(c, r, q) uint32_t W_##c##_##r##_##q;
#define LOADW(c, r, q) W_##c##_##r##_##q = wpb[(size_t)(((c)*16 + (r)*4 + (q)) * 1024) + tid];
#define DOTQ(c, r, q) a##r = fdot2u(W_##c##_##r##_##q, hq##q, a##r);

#define CHUNK(c)                                                   \
    {                                                              \
        uint4 hv = *(const uint4*)(hrow + (c) * 4);                \
        uint32_t hq0 = hv.x, hq1 = hv.y, hq2 = hv.z, hq3 = hv.w;   \
        FOR_Q(DOTQ, c, 0) FOR_Q(DOTQ, c, 1)                        \
        FOR_Q(DOTQ, c, 2) FOR_Q(DOTQ, c, 3)                        \
    }

#define LROW(c, r)                                                                        \
    {                                                                                     \
        uint4 wv = *(const uint4*)&wlds[(size_t)((((c) - 6) * 4 + (r)) * 1024 + tid) * 4];\
        a##r = fdot2u(wv.x, hq0, a##r);                                                   \
        a##r = fdot2u(wv.y, hq1, a##r);                                                   \
        a##r = fdot2u(wv.z, hq2, a##r);                                                   \
        a##r = fdot2u(wv.w, hq3, a##r);                                                   \
    }

#define CHUNKL(c)                                                  \
    {                                                              \
        uint4 hv = *(const uint4*)(hrow + (c) * 4);                \
        uint32_t hq0 = hv.x, hq1 = hv.y, hq2 = hv.z, hq3 = hv.w;   \
        LROW(c, 0) LROW(c, 1) LROW(c, 2) LROW(c, 3)                \
    }

#define DOT_PHASE                                                  \
    const uint32_t* hrow = (const uint32_t*)&hbuf[p][kg * 64];     \
    CHUNK(0) CHUNK(1) CHUNK(2) CHUNK(3) CHUNK(4) CHUNK(5)          \
    CHUNKL(6) CHUNKL(7)

__global__ __launch_bounds__(1024)
__attribute__((amdgpu_waves_per_eu(4, 4)))
void fused_rnn(const f16* __restrict__ xp0, const uint32_t* __restrict__ wp0,
               const uint32_t* __restrict__ wpih1, const uint32_t* __restrict__ wp1,
               const float* __restrict__ bs1,
               f16* __restrict__ h0seq, f16* __restrict__ xp1,
               f16* __restrict__ h1last,
               int* __restrict__ flag1, int* __restrict__ flag2) {
    const int bid = blockIdx.x;
    const int stage = bid >> 6;     // 0: rnn0, 1: proj, 2: rnn1
    const int row = bid & 63;
    const int tid = threadIdx.x;
    const int kg = tid >> 7;
    const int jq = tid & 127;
    __shared__ alignas(16) f16 hbuf[2][512];
    __shared__ float part[8][512];
    __shared__ uint32_t wlds[32 * 1024];   // 128 KB

    const uint32_t* wpb = (stage == 0) ? wp0 : (stage == 1) ? wpih1 : wp1;
    FOR_ALL(DECLW)
    FOR_ALL(LOADW)
#pragma unroll
    for (int i = 0; i < 32; ++i)
        wlds[i * 1024 + tid] = wpb[(size_t)96 * 1024 + (size_t)i * 1024 + tid];

    if (stage == 0) {
        // ---------------- layer-0 rnn ----------------
        if (tid < 512) hbuf[0][tid] = (f16)0.f;
        __syncthreads();
        const f16* xprow = xp0 + (size_t)row * 512 * 512;
        f16* hrow_out = h0seq + (size_t)row * 512 * 512;
        int* fl = flag1 + row;
        int p = 0;
        for (int t = 0; t < 512; ++t) {
            float xpv = 0.f;
            if (tid < 512) xpv = (float)xprow[(size_t)t * 512 + tid];
            float a0 = 0.f, a1 = 0.f, a2 = 0.f, a3 = 0.f;
            { DOT_PHASE }
            *(float4*)&part[kg][jq * 4] = make_float4(a0, a1, a2, a3);
            __syncthreads();
            if (tid < 512) {
                float s = xpv;
#pragma unroll
                for (int g = 0; g < 8; ++g) s += part[g][tid];
                float e = __expf(2.0f * s);
                float hn = 1.0f - 2.0f / (1.0f + e);
                f16 hh = (f16)hn;
                hbuf[p ^ 1][tid] = hh;
                hrow_out[(size_t)t * 512 + tid] = hh;
            }
            __syncthreads();
            if ((t & 7) == 7 && tid == 0) publish(fl, (t >> 3) + 1);
            p ^= 1;
        }
    } else if (stage == 1) {
        // ---------------- projection: xp1[t] = Wih1 * h0[t] + bias ----------------
        float bsv = (tid < 512) ? bs1[tid] : 0.f;
        const f16* h0row = h0seq + (size_t)row * 512 * 512;
        f16* xp1row = xp1 + (size_t)row * 512 * 512;
        int* flIn = flag1 + row;
        int* flOut = flag2 + row;
        poll_ge(flIn, 1);
        if (tid < 512) hbuf[0][tid] = h0row[tid];   // h0[0]
        __syncthreads();
        int p = 0;
        for (int t = 0; t < 512; ++t) {
            if (t > 0 && (t & 7) == 0) {
                poll_ge(flIn, (t >> 3) + 1);
                if (tid < 512) hbuf[p][tid] = h0row[(size_t)t * 512 + tid];
                __syncthreads();
            }
            const bool pv = ((t + 1) < 512) && (((t + 1) & 7) != 0);
            f16 hnext = (f16)0.f;
            if (pv && tid < 512) hnext = h0row[(size_t)(t + 1) * 512 + tid];  // prefetch
            float a0 = 0.f, a1 = 0.f, a2 = 0.f, a3 = 0.f;
            { DOT_PHASE }
            *(float4*)&part[kg][jq * 4] = make_float4(a0, a1, a2, a3);
            __syncthreads();
            if (tid < 512) {
                float s = bsv;
#pragma unroll
                for (int g = 0; g < 8; ++g) s += part[g][tid];
                xp1row[(size_t)t * 512 + tid] = (f16)s;
                if (pv) hbuf[p ^ 1][tid] = hnext;
            }
            __syncthreads();
            if ((t & 7) == 7 && tid == 0) publish(flOut, (t >> 3) + 1);
            if (pv) p ^= 1;
        }
    } else {
        // ---------------- layer-1 rnn ----------------
        if (tid < 512) hbuf[0][tid] = (f16)0.f;
        __syncthreads();
        const f16* xprow = xp1 + (size_t)row * 512 * 512;
        f16* hlast = h1last + (size_t)row * 512;
        int* fl = flag2 + row;
        int p = 0;
        for (int t = 0; t < 512; ++t) {
            if ((t & 7) == 0) poll_ge(fl, (t >> 3) + 1);
            float xpv = 0.f;
            if (tid < 512) xpv = (float)xprow[(size_t)t * 512 + tid];
            float a0 = 0.f, a1 = 0.f, a2 = 0.f, a3 = 0.f;
            { DOT_PHASE }
            *(float4*)&part[kg][jq * 4] = make_float4(a0, a1, a2, a3);
            __syncthreads();
            if (tid < 512) {
                float s = xpv;
#pragma unroll
                for (int g = 0; g < 8; ++g) s += part[g][tid];
                float e = __expf(2.0f * s);
                float hn = 1.0f - 2.0f / (1.0f + e);
                f16 hh = (f16)hn;
                hbuf[p ^ 1][tid] = hh;
                if (t == 511) hlast[tid] = hh;
            }
            __syncthreads();
            p ^= 1;
        }
    }
}

// ---------------- final FC ----------------
__global__ __launch_bounds__(512) void fc_kernel(const f16* __restrict__ h1,
                                                 const float* __restrict__ Wfc,
                                                 const float* __restrict__ bfc,
                                                 float* __restrict__ out) {
    int b = blockIdx.x, tid = threadIdx.x;
    __shared__ float red[8];
    float v = (float)h1[(size_t)b * 512 + tid] * Wfc[tid];
#pragma unroll
    for (int off = 32; off > 0; off >>= 1) v += __shfl_down(v, off, 64);
    if ((tid & 63) == 0) red[tid >> 6] = v;
    __syncthreads();
    if (tid == 0) {
        float s = bfc[0];
#pragma unroll
        for (int g = 0; g < 8; ++g) s += red[g];
        out[b] = s;
    }
}

extern "C" void kernel_launch(void* const* d_in, const int* in_sizes, int n_in,
                              void* d_out, int out_size, void* d_ws, size_t ws_size,
                              hipStream_t stream) {
    const float* x    = (const float*)d_in[0];
    const float* Wih0 = (const float*)d_in[1];
    const float* Whh0 = (const float*)d_in[2];
    const float* bih0 = (const float*)d_in[3];
    const float* bhh0 = (const float*)d_in[4];
    const float* Wih1 = (const float*)d_in[5];
    const float* Whh1 = (const float*)d_in[6];
    const float* bih1 = (const float*)d_in[7];
    const float* bhh1 = (const float*)d_in[8];
    const float* Wfc  = (const float*)d_in[9];
    const float* bfc  = (const float*)d_in[10];
    float* out = (float*)d_out;

    char* ws = (char*)d_ws;
    size_t off = 0;
    auto alloc = [&](size_t bytes) -> void* {
        void* p = ws + off;
        off += (bytes + 255) & ~(size_t)255;
        return p;
    };
    const size_t MTD = (size_t)64 * 512 * 512;
    f16* x16    = (f16*)alloc(MTD * 2);
    f16* h016   = (f16*)alloc(MTD * 2);
    f16* xpb    = (f16*)alloc(MTD * 2);
    f16* xp1b   = (f16*)alloc(MTD * 2);
    f16* wih016 = (f16*)alloc((size_t)512 * 512 * 2);
    uint32_t* wp0   = (uint32_t*)alloc((size_t)131072 * 4);
    uint32_t* wp1   = (uint32_t*)alloc((size_t)131072 * 4);
    uint32_t* wpih1 = (uint32_t*)alloc((size_t)131072 * 4);
    float* bs0 = (float*)alloc(512 * 4);
    float* bs1 = (float*)alloc(512 * 4);
    f16* h1last = (f16*)alloc((size_t)64 * 512 * 2);
    int* flags = (int*)alloc(128 * 4);   // flag1[64] + flag2[64]

    // prep
    cvt_kernel<<<2048, 256, 0, stream>>>(x, x16, (int)(MTD / 4));
    cvt_kernel<<<256, 256, 0, stream>>>(Wih0, wih016, 512 * 512 / 4);
    bsum_kernel<<<1, 512, 0, stream>>>(bih0, bhh0, bs0);
    bsum_kernel<<<1, 512, 0, stream>>>(bih1, bhh1, bs1);
    pack_whh<<<512, 256, 0, stream>>>(Whh0, wp0);
    pack_whh<<<512, 256, 0, stream>>>(Whh1, wp1);
    pack_whh<<<512, 256, 0, stream>>>(Wih1, wpih1);
    hipMemsetAsync(flags, 0, 128 * 4, stream);

    // layer-0 xproj GEMM
    gemm_xp<<<1024, 256, 0, stream>>>(x16, wih016, bs0, xpb);
    // fused pipelined recurrence (layer0 -> proj -> layer1)
    fused_rnn<<<192, 1024, 0, stream>>>(xpb, wp0, wpih1, wp1, bs1,
                                        h016, xp1b, h1last, flags, flags + 64);
    // head
    fc_kernel<<<64, 512, 0, stream>>>(h1last, Wfc, bfc, out);
}